// Round 18
// baseline (1716.539 us; speedup 1.0000x reference)
//
#include <hip/hip_runtime.h>
#include <math.h>

#define B_ 512
#define N_ 20
#define H_ 450
#define L_ 56
#define V_ 780
#define T_ 38
#define NNODES (B_*N_)        // 10240
#define NEDGES (B_*2*(N_-1))  // 19456
#define NPROWS ((T_+1)*B_)    // 19968
#define KS 480                // m/rm/xb row stride (bf16 elements)
#define NT 2                  // trees per block -> 256 blocks
#define ASTQ 528              // fp8 A-tile LDS row stride bytes (512 data + 16 pad)
#define HSTR 456              // hb/hm/hrm/XW row stride (bf16 elements)
#define KQ 512                // q-head K: [hb 456 | tv 56]
#define KPP 992               // p-head K: [xb 480 | hb 456 | tv 56]
#define LDL 784               // logits row stride (bf16)

typedef __attribute__((ext_vector_type(8))) short bf16x8;
typedef __attribute__((ext_vector_type(4))) float f32x4;
typedef __attribute__((ext_vector_type(2))) long i64x2;

__device__ __forceinline__ float sigmoidf_(float v){ return 1.0f/(1.0f+expf(-v)); }

__device__ __forceinline__ unsigned short f2b(float x){
  unsigned int u = __float_as_uint(x);
  unsigned int r = (u + 0x7fffu + ((u >> 16) & 1u)) >> 16;
  return (unsigned short)r;
}
__device__ __forceinline__ float b2f(unsigned int v){
  return __uint_as_float((v & 0xffffu) << 16);
}
__device__ __forceinline__ unsigned int pack2(float lo, float hi){
  return (unsigned int)f2b(lo) | ((unsigned int)f2b(hi) << 16);
}
// f32 -> OCP e4m3fn, RNE, saturating (validated R11: absmax 9.5e-5)
__device__ __forceinline__ unsigned char f2e4m3(float x){
  unsigned int u = __float_as_uint(x);
  unsigned char sgn = (u >> 24) & 0x80;
  unsigned int au = u & 0x7fffffffu;
  if (au >= 0x43e00000u) return sgn | 0x7e;
  if (au < 0x3c800000u){
    float t = __uint_as_float(au) * 512.f;
    int q = (int)rintf(t);
    if (q >= 8) return sgn | 0x08;
    return sgn | (unsigned char)q;
  }
  unsigned int r = au + 0x7ffffu + ((au >> 20) & 1u);
  if (r >= 0x43e00000u) return sgn | 0x7e;
  int e = (int)((r >> 23) & 0xff) - 120;
  unsigned int m = (r >> 20) & 7u;
  return sgn | (unsigned char)((e << 3) | m);
}
// fragment-major offset within a 512B row: k -> [kh][it][j]
__device__ __forceinline__ int foff_(int k){
  return ((k >> 3) & 3)*128 + (k >> 5)*8 + (k & 7);
}

// ---------------------------------------------------------------------------
__global__ __launch_bounds__(256) void k_gather_xb(const float* __restrict__ emb,
    const int* __restrict__ wid, unsigned short* __restrict__ xb){
  int w = blockIdx.x*4 + (threadIdx.x>>6), lane = threadIdx.x & 63;
  if (w >= NNODES) return;
  const float2* src = (const float2*)(emb + (size_t)wid[w]*H_);
  unsigned int* dst = (unsigned int*)(xb + (size_t)w*KS);
  for (int j2 = lane; j2 < 240; j2 += 64){
    unsigned int v = 0;
    if (j2 < 225){ float2 f = src[j2]; v = pack2(f.x, f.y); }
    dst[j2] = v;
  }
}

// fused weight-prep: transposes + tvb (bf16 parts; unused WzB/WhB/UrT kept for simplicity)
__global__ void k_wtall(const float* __restrict__ Wz, const float* __restrict__ Wh,
    const float* __restrict__ Ur, const float* __restrict__ Wr,
    const float* __restrict__ Ww, const float* __restrict__ Uw,
    const float* __restrict__ Wo, const float* __restrict__ tv,
    unsigned short* __restrict__ WzB, unsigned short* __restrict__ WhB,
    unsigned short* __restrict__ UrT, unsigned short* __restrict__ WzTop,
    unsigned short* __restrict__ WhTop, unsigned short* __restrict__ WrT,
    unsigned short* __restrict__ WwT, unsigned short* __restrict__ UwT,
    unsigned short* __restrict__ WoT, unsigned short* __restrict__ tvb){
  int bid = blockIdx.x;
  if (bid < 512*6){
    int seg = bid >> 9, c = bid & 511;
    const float* src; unsigned short* dst; int rowbase;
    switch(seg){
      case 0: src = Wz; dst = WzB; rowbase = 450; break;
      case 1: src = Wh; dst = WhB; rowbase = 450; break;
      case 2: src = Ur; dst = UrT; rowbase = 0; break;
      case 3: src = Wz; dst = WzTop; rowbase = 0; break;
      case 4: src = Wh; dst = WhTop; rowbase = 0; break;
      default: src = Wr; dst = WrT; rowbase = 0; break;
    }
    unsigned short* drow = dst + (size_t)c*KS;
    for (int k = threadIdx.x; k < KS; k += blockDim.x){
      float v = 0.f;
      if (c < 450 && k < 450) v = src[(size_t)(rowbase + k)*450 + c];
      drow[k] = f2b(v);
    }
  } else if (bid < 512*7){
    int c = bid - 512*6;
    unsigned short* drow = WwT + (size_t)c*KQ;
    for (int k = threadIdx.x; k < KQ; k += blockDim.x){
      float v = 0.f;
      if (c < 450){
        if (k < 450) v = Ww[(size_t)k*450 + c];
        else if (k >= 456) v = Ww[(size_t)(450 + k - 456)*450 + c];
      }
      drow[k] = f2b(v);
    }
  } else if (bid < 512*8){
    int c = bid - 512*7;
    unsigned short* drow = UwT + (size_t)c*KPP;
    for (int k = threadIdx.x; k < KPP; k += blockDim.x){
      float v = 0.f;
      if (c < 450){
        if (k < 450) v = Uw[(size_t)k*450 + c];
        else if (k >= 480 && k < 930) v = Uw[(size_t)(450 + k - 480)*450 + c];
        else if (k >= 936) v = Uw[(size_t)(900 + k - 936)*450 + c];
      }
      drow[k] = f2b(v);
    }
  } else if (bid < 512*8 + 832){
    int c = bid - 512*8;
    unsigned short* drow = WoT + (size_t)c*512;
    for (int k = threadIdx.x; k < 512; k += blockDim.x){
      float v = 0.f;
      if (c < V_ && k < 450) v = Wo[(size_t)k*V_ + c];
      drow[k] = f2b(v);
    }
  } else {
    int b = bid - (512*8 + 832);
    unsigned short* drow = tvb + (size_t)b*64;
    for (int k = threadIdx.x; k < 64; k += blockDim.x)
      drow[k] = f2b((k < L_) ? tv[b*L_ + k] : 0.f);
  }
}

// weight -> fp8 fragment-major [col][512B], scale x16, zero-padded
__global__ void k_wt8(const float* __restrict__ W, int Kact, int Nact,
                      unsigned char* __restrict__ dst){
  int c = blockIdx.x;
  unsigned char* drow = dst + (size_t)c*512;
  for (int k = threadIdx.x; k < 512; k += blockDim.x){
    float v = 0.f;
    if (c < Nact && k < Kact) v = W[(size_t)k*Nact + c] * 16.f;
    drow[foff_(k)] = f2e4m3(v);
  }
}

// ---------------------------------------------------------------------------
struct ScanP {
  const unsigned char *WzQ, *WhQ, *UrQ;         // fp8 [512][512B] fragment-major, x16
  const unsigned short *XWz, *XWh, *XWr;        // bf16 [10240][HSTR], bias folded
  const int *edge_src, *edge_dst, *step_eid;
  unsigned short *m, *rm;                       // bf16 [NEDGES][480]
  unsigned short *hm, *hrm;                     // bf16 [NNODES][HSTR]
  unsigned short *hb;                           // bf16 [T*B][HSTR]
};

// R15 champion scan with fp8 GEMM operands (chunked fragment-major loads:
// half the B bytes AND half the B load count). State stays bf16.
__global__ __launch_bounds__(1024, 4) void k_scan_tree(ScanP p){
  __shared__ unsigned char A1s[16*ASTQ];   // fp8 [s]
  __shared__ unsigned char A2s[16*ASTQ];   // fp8 [arm]
  __shared__ unsigned char A3s[16*ASTQ];   // fp8 [m_new]
  __shared__ unsigned short SLb[NT*HSTR];  // bf16 s (for (1-z)*s mix)
  __shared__ unsigned short sZ[NT*HSTR], sH[NT*HSTR], sR[NT*HSTR];
  __shared__ int s_eoff[T_][NT], s_roff[T_][NT], s_srcH[T_][NT], s_dstH[T_][NT];

  const int tid = threadIdx.x;
  const int lane = tid & 63, l15 = lane & 15, kh = lane >> 4;
  const int wv = tid >> 6;
  const int r0 = blockIdx.x * NT;
  const int c_0 = wv*32 + l15, c_1 = c_0 + 16;

  const unsigned char* qWz0 = p.WzQ + (size_t)c_0*512 + kh*128;
  const unsigned char* qWz1 = p.WzQ + (size_t)c_1*512 + kh*128;
  const unsigned char* qWh0 = p.WhQ + (size_t)c_0*512 + kh*128;
  const unsigned char* qWh1 = p.WhQ + (size_t)c_1*512 + kh*128;
  const unsigned char* qUr0 = p.UrQ + (size_t)c_0*512 + kh*128;
  const unsigned char* qUr1 = p.UrQ + (size_t)c_1*512 + kh*128;
  const unsigned char* aA1q = A1s + l15*ASTQ + kh*128;
  const unsigned char* aA2q = A2s + l15*ASTQ + kh*128;
  const unsigned char* aA3q = A3s + l15*ASTQ + kh*128;

  for (int idx = tid; idx < 16*ASTQ/4; idx += 1024){
    ((unsigned int*)A1s)[idx] = 0u; ((unsigned int*)A2s)[idx] = 0u;
    ((unsigned int*)A3s)[idx] = 0u;
  }
  for (int idx = tid; idx < T_*NT; idx += 1024){
    int t = idx / NT, rl = idx % NT;
    int e = p.step_eid[t*B_ + r0 + rl];
    s_eoff[t][rl] = e*KS;
    s_roff[t][rl] = (e ^ 1)*KS;
    s_srcH[t][rl] = p.edge_src[e]*HSTR;
    s_dstH[t][rl] = p.edge_dst[e]*HSTR;
  }
  __syncthreads();

  for (int t = 0; t < T_; ++t){
    // gate-B ring prefetch (chunks 0..2; hides under phase1)
    i64x2 rz0[3], rz1[3], rh0[3], rh1[3];
    #pragma unroll
    for (int i = 0; i < 3; ++i){
      rz0[i] = *(const i64x2*)(qWz0 + i*16);
      rz1[i] = *(const i64x2*)(qWz1 + i*16);
      rh0[i] = *(const i64x2*)(qWh0 + i*16);
      rh1[i] = *(const i64x2*)(qWh1 + i*16);
    }

    // phase1: A1=[s]=hm[src]-m[rev] fp8, A2=[arm]=hrm[src]-rm[rev] fp8, SLb=s bf16;
    // stage XW rows
    if (tid < NT*57){
      int rl = tid / 57, g = tid - rl*57;
      int j = g*8;
      uint4 hm4 = *(const uint4*)(p.hm  + s_srcH[t][rl] + j);
      uint4 hr4 = *(const uint4*)(p.hrm + s_srcH[t][rl] + j);
      uint4 mr4 = *(const uint4*)(p.m   + s_roff[t][rl] + j);
      uint4 rr4 = *(const uint4*)(p.rm  + s_roff[t][rl] + j);
      float f0 = b2f(hm4.x)-b2f(mr4.x), f1 = b2f(hm4.x>>16)-b2f(mr4.x>>16);
      float f2 = b2f(hm4.y)-b2f(mr4.y), f3 = b2f(hm4.y>>16)-b2f(mr4.y>>16);
      float f4 = b2f(hm4.z)-b2f(mr4.z), f5 = b2f(hm4.z>>16)-b2f(mr4.z>>16);
      float f6 = b2f(hm4.w)-b2f(mr4.w), f7 = b2f(hm4.w>>16)-b2f(mr4.w>>16);
      float a0 = b2f(hr4.x)-b2f(rr4.x), a1 = b2f(hr4.x>>16)-b2f(rr4.x>>16);
      float a2 = b2f(hr4.y)-b2f(rr4.y), a3 = b2f(hr4.y>>16)-b2f(rr4.y>>16);
      float a4 = b2f(hr4.z)-b2f(rr4.z), a5 = b2f(hr4.z>>16)-b2f(rr4.z>>16);
      float a6 = b2f(hr4.w)-b2f(rr4.w), a7 = b2f(hr4.w>>16)-b2f(rr4.w>>16);
      int fo = ((j>>3)&3)*128 + (j>>5)*8;
      uint2 w1, w2;
      w1.x = (unsigned)f2e4m3(f0) | ((unsigned)f2e4m3(f1)<<8) | ((unsigned)f2e4m3(f2)<<16) | ((unsigned)f2e4m3(f3)<<24);
      w1.y = (unsigned)f2e4m3(f4) | ((unsigned)f2e4m3(f5)<<8) | ((unsigned)f2e4m3(f6)<<16) | ((unsigned)f2e4m3(f7)<<24);
      w2.x = (unsigned)f2e4m3(a0) | ((unsigned)f2e4m3(a1)<<8) | ((unsigned)f2e4m3(a2)<<16) | ((unsigned)f2e4m3(a3)<<24);
      w2.y = (unsigned)f2e4m3(a4) | ((unsigned)f2e4m3(a5)<<8) | ((unsigned)f2e4m3(a6)<<16) | ((unsigned)f2e4m3(a7)<<24);
      *(uint2*)(A1s + rl*ASTQ + fo) = w1;
      *(uint2*)(A2s + rl*ASTQ + fo) = w2;
      uint4 sb; sb.x = pack2(f0,f1); sb.y = pack2(f2,f3); sb.z = pack2(f4,f5); sb.w = pack2(f6,f7);
      *(uint4*)(SLb + rl*HSTR + j) = sb;
    } else if (tid >= 128 && tid < 128 + 3*NT*57){
      int idx2 = tid - 128;
      int mat = idx2 / (NT*57), rem = idx2 - mat*(NT*57);
      int rl = rem / 57, g = rem - rl*57;
      int row = (mat == 2) ? s_dstH[t][rl] : s_srcH[t][rl];
      const unsigned short* src = (mat == 0) ? p.XWz : (mat == 1) ? p.XWh : p.XWr;
      unsigned short* d = (mat == 0) ? sZ : (mat == 1) ? sH : sR;
      *(uint4*)(d + rl*HSTR + g*8) = *(const uint4*)(src + row + g*8);
    }
    __syncthreads();   // (A)

    // gate K-loop: 8 chunks x 2 MFMA/stream, fp8, ring refill
    f32x4 accZ0 = {}, accZ1 = {}, accH0 = {}, accH1 = {};
    #pragma unroll
    for (int c = 0; c < 8; ++c){
      const int sl = c % 3;
      i64x2 a1 = *(const i64x2*)(aA1q + c*16);
      i64x2 a2 = *(const i64x2*)(aA2q + c*16);
      accZ0 = __builtin_amdgcn_mfma_f32_16x16x32_fp8_fp8(a1.x, rz0[sl].x, accZ0, 0,0,0);
      accZ0 = __builtin_amdgcn_mfma_f32_16x16x32_fp8_fp8(a1.y, rz0[sl].y, accZ0, 0,0,0);
      accZ1 = __builtin_amdgcn_mfma_f32_16x16x32_fp8_fp8(a1.x, rz1[sl].x, accZ1, 0,0,0);
      accZ1 = __builtin_amdgcn_mfma_f32_16x16x32_fp8_fp8(a1.y, rz1[sl].y, accZ1, 0,0,0);
      accH0 = __builtin_amdgcn_mfma_f32_16x16x32_fp8_fp8(a2.x, rh0[sl].x, accH0, 0,0,0);
      accH0 = __builtin_amdgcn_mfma_f32_16x16x32_fp8_fp8(a2.y, rh0[sl].y, accH0, 0,0,0);
      accH1 = __builtin_amdgcn_mfma_f32_16x16x32_fp8_fp8(a2.x, rh1[sl].x, accH1, 0,0,0);
      accH1 = __builtin_amdgcn_mfma_f32_16x16x32_fp8_fp8(a2.y, rh1[sl].y, accH1, 0,0,0);
      if (c < 5){
        rz0[sl] = *(const i64x2*)(qWz0 + (c+3)*16);
        rz1[sl] = *(const i64x2*)(qWz1 + (c+3)*16);
        rh0[sl] = *(const i64x2*)(qWh0 + (c+3)*16);
        rh1[sl] = *(const i64x2*)(qWh1 + (c+3)*16);
      }
    }

    // rgate-B ring prefetch (overlaps epilogue1)
    i64x2 ru0[3], ru1[3];
    #pragma unroll
    for (int i = 0; i < 3; ++i){
      ru0[i] = *(const i64x2*)(qUr0 + i*16);
      ru1[i] = *(const i64x2*)(qUr1 + i*16);
    }

    // epilogue1: m_new -> global m (bf16) + A3s (fp8); hm RMW; hb snapshot
    if (kh == 0){
      #pragma unroll
      for (int n = 0; n < 2; ++n){
        int cc = wv*32 + n*16 + l15;
        if (cc < H_){
          f32x4 aZ = n ? accZ1 : accZ0;
          f32x4 aH = n ? accH1 : accH0;
          #pragma unroll
          for (int reg = 0; reg < NT; ++reg){
            int rl = reg;
            float z  = sigmoidf_(aZ[reg]*0.0625f + b2f(sZ[rl*HSTR + cc]));
            float th = tanhf   (aH[reg]*0.0625f + b2f(sH[rl*HSTR + cc]));
            float s_ = b2f(SLb[rl*HSTR + cc]);
            float mn = (1.f - z)*s_ + z*th;
            p.m[s_eoff[t][rl] + cc] = f2b(mn);
            A3s[rl*ASTQ + foff_(cc)] = f2e4m3(mn);
            float hv = b2f(p.hm[s_dstH[t][rl] + cc]) + mn;
            p.hm[s_dstH[t][rl] + cc] = f2b(hv);
            p.hb[(size_t)(t*B_ + r0 + rl)*HSTR + cc] = f2b(hv);
          }
        }
      }
    }
    __syncthreads();   // (C)

    // rgate K-loop: R = m_new@Ur (fp8)
    f32x4 accR0 = {}, accR1 = {};
    #pragma unroll
    for (int c = 0; c < 8; ++c){
      const int sl = c % 3;
      i64x2 a = *(const i64x2*)(aA3q + c*16);
      accR0 = __builtin_amdgcn_mfma_f32_16x16x32_fp8_fp8(a.x, ru0[sl].x, accR0, 0,0,0);
      accR0 = __builtin_amdgcn_mfma_f32_16x16x32_fp8_fp8(a.y, ru0[sl].y, accR0, 0,0,0);
      accR1 = __builtin_amdgcn_mfma_f32_16x16x32_fp8_fp8(a.x, ru1[sl].x, accR1, 0,0,0);
      accR1 = __builtin_amdgcn_mfma_f32_16x16x32_fp8_fp8(a.y, ru1[sl].y, accR1, 0,0,0);
      if (c < 5){
        ru0[sl] = *(const i64x2*)(qUr0 + (c+3)*16);
        ru1[sl] = *(const i64x2*)(qUr1 + (c+3)*16);
      }
    }

    // epilogue2: rm store; hrm RMW (m_new re-read from global bf16, same lane)
    if (kh == 0){
      #pragma unroll
      for (int n = 0; n < 2; ++n){
        int cc = wv*32 + n*16 + l15;
        if (cc < H_){
          f32x4 aR = n ? accR1 : accR0;
          #pragma unroll
          for (int reg = 0; reg < NT; ++reg){
            int rl = reg;
            float r_ = sigmoidf_(aR[reg]*0.0625f + b2f(sR[rl*HSTR + cc]));
            float mn = b2f(p.m[s_eoff[t][rl] + cc]);
            float rv = r_*mn;
            p.rm[s_eoff[t][rl] + cc] = f2b(rv);
            float hv = b2f(p.hrm[s_dstH[t][rl] + cc]) + rv;
            p.hrm[s_dstH[t][rl] + cc] = f2b(hv);
          }
        }
      }
    }
    __syncthreads();   // (D)
  }
}

// ---------------------------------------------------------------------------
// Generic head GEMM (plain A): 64x64, 4 waves, BK=32, K-major bf16 B.
__global__ __launch_bounds__(256) void k_head_mfma(
    const unsigned short* __restrict__ A, const unsigned short* __restrict__ BT, int K,
    const float* __restrict__ bias, int Nact, int relu,
    float* __restrict__ outF, int ldF, unsigned short* __restrict__ outB, int ldB)
{
  __shared__ unsigned short As[64*40], Bs[64*40];
  const int tid = threadIdx.x;
  const int gr0 = blockIdx.y*64, gc0 = blockIdx.x*64;
  const int lane = tid & 63;
  const int w = tid >> 6, wr = w >> 1, wc = w & 1;
  const int l15 = lane & 15, kh = lane >> 4;
  const int sr = tid >> 2, sj = (tid & 3) * 8;
  f32x4 acc[2][2] = {};
  for (int kt = 0; kt < K; kt += 32){
    __syncthreads();
    *(float4*)&As[sr*40 + sj] = *(const float4*)&A[(size_t)(gr0+sr)*K + kt + sj];
    *(float4*)&Bs[sr*40 + sj] = *(const float4*)&BT[(size_t)(gc0+sr)*K + kt + sj];
    __syncthreads();
    bf16x8 a0 = *(const bf16x8*)&As[(wr*32      + l15)*40 + kh*8];
    bf16x8 a1 = *(const bf16x8*)&As[(wr*32 + 16 + l15)*40 + kh*8];
    bf16x8 b0 = *(const bf16x8*)&Bs[(wc*32      + l15)*40 + kh*8];
    bf16x8 b1 = *(const bf16x8*)&Bs[(wc*32 + 16 + l15)*40 + kh*8];
    acc[0][0] = __builtin_amdgcn_mfma_f32_16x16x32_bf16(a0,b0,acc[0][0],0,0,0);
    acc[0][1] = __builtin_amdgcn_mfma_f32_16x16x32_bf16(a0,b1,acc[0][1],0,0,0);
    acc[1][0] = __builtin_amdgcn_mfma_f32_16x16x32_bf16(a1,b0,acc[1][0],0,0,0);
    acc[1][1] = __builtin_amdgcn_mfma_f32_16x16x32_bf16(a1,b1,acc[1][1],0,0,0);
  }
  #pragma unroll
  for (int mi = 0; mi < 2; ++mi){
    #pragma unroll
    for (int n = 0; n < 2; ++n){
      int c = gc0 + wc*32 + n*16 + l15;
      float bc = (c < Nact) ? bias[c] : 0.f;
      #pragma unroll
      for (int reg = 0; reg < 4; ++reg){
        int r = gr0 + wr*32 + mi*16 + kh*4 + reg;
        float v = acc[mi][n][reg] + bc;
        if (relu) v = fmaxf(v, 0.f);
        if (outF && c < Nact) outF[(size_t)r*ldF + c] = v;
        if (outB && c < ldB)  outB[(size_t)r*ldB + c] = (c < Nact) ? f2b(v) : (unsigned short)0;
      }
    }
  }
}

// XW precompute: 3 GEMMs in one launch (blockIdx.z selects matrix).
__global__ __launch_bounds__(256) void k_xw(const unsigned short* __restrict__ xb,
    const unsigned short* __restrict__ WzTop, const unsigned short* __restrict__ WhTop,
    const unsigned short* __restrict__ WrT,
    const float* __restrict__ bz, const float* __restrict__ bh, const float* __restrict__ br,
    unsigned short* __restrict__ XWz, unsigned short* __restrict__ XWh,
    unsigned short* __restrict__ XWr)
{
  __shared__ unsigned short As[64*40], Bs[64*40];
  const unsigned short* BT = (blockIdx.z == 0) ? WzTop : (blockIdx.z == 1) ? WhTop : WrT;
  const float* bias        = (blockIdx.z == 0) ? bz    : (blockIdx.z == 1) ? bh    : br;
  unsigned short* outB     = (blockIdx.z == 0) ? XWz   : (blockIdx.z == 1) ? XWh   : XWr;
  const int tid = threadIdx.x;
  const int gr0 = blockIdx.y*64, gc0 = blockIdx.x*64;
  const int lane = tid & 63;
  const int w = tid >> 6, wr = w >> 1, wc = w & 1;
  const int l15 = lane & 15, kh = lane >> 4;
  const int sr = tid >> 2, sj = (tid & 3) * 8;
  f32x4 acc[2][2] = {};
  for (int kt = 0; kt < KS; kt += 32){
    __syncthreads();
    *(float4*)&As[sr*40 + sj] = *(const float4*)&xb[(size_t)(gr0+sr)*KS + kt + sj];
    *(float4*)&Bs[sr*40 + sj] = *(const float4*)&BT[(size_t)(gc0+sr)*KS + kt + sj];
    __syncthreads();
    bf16x8 a0 = *(const bf16x8*)&As[(wr*32      + l15)*40 + kh*8];
    bf16x8 a1 = *(const bf16x8*)&As[(wr*32 + 16 + l15)*40 + kh*8];
    bf16x8 b0 = *(const bf16x8*)&Bs[(wc*32      + l15)*40 + kh*8];
    bf16x8 b1 = *(const bf16x8*)&Bs[(wc*32 + 16 + l15)*40 + kh*8];
    acc[0][0] = __builtin_amdgcn_mfma_f32_16x16x32_bf16(a0,b0,acc[0][0],0,0,0);
    acc[0][1] = __builtin_amdgcn_mfma_f32_16x16x32_bf16(a0,b1,acc[0][1],0,0,0);
    acc[1][0] = __builtin_amdgcn_mfma_f32_16x16x32_bf16(a1,b0,acc[1][0],0,0,0);
    acc[1][1] = __builtin_amdgcn_mfma_f32_16x16x32_bf16(a1,b1,acc[1][1],0,0,0);
  }
  #pragma unroll
  for (int mi = 0; mi < 2; ++mi){
    #pragma unroll
    for (int n = 0; n < 2; ++n){
      int c = gc0 + wc*32 + n*16 + l15;
      if (c >= HSTR) continue;
      float bc = (c < H_) ? bias[c] : 0.f;
      #pragma unroll
      for (int reg = 0; reg < 4; ++reg){
        int r = gr0 + wr*32 + mi*16 + kh*4 + reg;
        outB[(size_t)r*HSTR + c] = (c < H_) ? f2b(acc[mi][n][reg] + bc) : (unsigned short)0;
      }
    }
  }
}

// q-hidden GEMM with virtual A (hb|tvb via q_rows). K=512.
__global__ __launch_bounds__(256) void k_head_q(const unsigned short* __restrict__ hb,
    const unsigned short* __restrict__ tvb, const int* __restrict__ q_rows,
    const unsigned short* __restrict__ BT, const float* __restrict__ bw,
    unsigned short* __restrict__ hqb, int nq)
{
  __shared__ unsigned short As[64*40], Bs[64*40];
  __shared__ int s_hrow[64], s_b[64];
  const int tid = threadIdx.x;
  const int gr0 = blockIdx.y*64, gc0 = blockIdx.x*64;
  if (tid < 64){
    int gi = gr0 + tid;
    int row = (gi < nq) ? q_rows[gi] : 0;
    s_hrow[tid] = (row < B_) ? -1 : row - B_;
    s_b[tid] = row & (B_-1);
  }
  const int lane = tid & 63;
  const int w = tid >> 6, wr = w >> 1, wc = w & 1;
  const int l15 = lane & 15, kh = lane >> 4;
  const int sr = tid >> 2, sj = (tid & 3) * 8;
  f32x4 acc[2][2] = {};
  for (int kt = 0; kt < KQ; kt += 32){
    __syncthreads();
    int gk = kt + sj;
    uint4 av;
    if (gk < 456){
      int hr = s_hrow[sr];
      if (hr < 0){ av.x = av.y = av.z = av.w = 0u; }
      else av = *(const uint4*)(hb + (size_t)hr*HSTR + gk);
    } else {
      av = *(const uint4*)(tvb + (size_t)s_b[sr]*64 + (gk - 456));
    }
    *(uint4*)&As[sr*40 + sj] = av;
    *(float4*)&Bs[sr*40 + sj] = *(const float4*)&BT[(size_t)(gc0+sr)*KQ + gk];
    __syncthreads();
    bf16x8 a0 = *(const bf16x8*)&As[(wr*32      + l15)*40 + kh*8];
    bf16x8 a1 = *(const bf16x8*)&As[(wr*32 + 16 + l15)*40 + kh*8];
    bf16x8 b0 = *(const bf16x8*)&Bs[(wc*32      + l15)*40 + kh*8];
    bf16x8 b1 = *(const bf16x8*)&Bs[(wc*32 + 16 + l15)*40 + kh*8];
    acc[0][0] = __builtin_amdgcn_mfma_f32_16x16x32_bf16(a0,b0,acc[0][0],0,0,0);
    acc[0][1] = __builtin_amdgcn_mfma_f32_16x16x32_bf16(a0,b1,acc[0][1],0,0,0);
    acc[1][0] = __builtin_amdgcn_mfma_f32_16x16x32_bf16(a1,b0,acc[1][0],0,0,0);
    acc[1][1] = __builtin_amdgcn_mfma_f32_16x16x32_bf16(a1,b1,acc[1][1],0,0,0);
  }
  #pragma unroll
  for (int mi = 0; mi < 2; ++mi){
    #pragma unroll
    for (int n = 0; n < 2; ++n){
      int c = gc0 + wc*32 + n*16 + l15;
      float bc = (c < H_) ? bw[c] : 0.f;
      #pragma unroll
      for (int reg = 0; reg < 4; ++reg){
        int r = gr0 + wr*32 + mi*16 + kh*4 + reg;
        float v = fmaxf(acc[mi][n][reg] + bc, 0.f);
        hqb[(size_t)r*KQ + c] = (c < H_) ? f2b(v) : (unsigned short)0;
      }
    }
  }
}

// p-head GEMM with virtual A (xb|hb|tvb) + fused Us-dot. K=992.
__global__ __launch_bounds__(256) void k_head_p2(const unsigned short* __restrict__ xb,
    const unsigned short* __restrict__ hb, const unsigned short* __restrict__ tvb,
    const int* __restrict__ root_ids, const int* __restrict__ step_v,
    const unsigned short* __restrict__ BT, const float* __restrict__ bu_,
    const float* __restrict__ Us, float* __restrict__ plog)
{
  __shared__ unsigned short As[64*40], Bs[64*40];
  __shared__ int s_xrow[64], s_hrow[64], s_b[64];
  const int tid = threadIdx.x;
  const int gr0 = blockIdx.y*64, gc0 = blockIdx.x*64;
  if (tid < 64){
    int i = gr0 + tid;
    int b = i & (B_-1);
    s_b[tid] = b;
    s_xrow[tid] = (i < B_) ? root_ids[b] : step_v[i - B_];
    s_hrow[tid] = (i < B_) ? -1 : i - B_;
  }
  const int lane = tid & 63;
  const int w = tid >> 6, wr = w >> 1, wc = w & 1;
  const int l15 = lane & 15, kh = lane >> 4;
  const int sr = tid >> 2, sj = (tid & 3) * 8;
  f32x4 acc[2][2] = {};
  for (int kt = 0; kt < KPP; kt += 32){
    __syncthreads();
    int gk = kt + sj;
    uint4 av;
    if (gk < 480){
      av = *(const uint4*)(xb + (size_t)s_xrow[sr]*KS + gk);
    } else if (gk < 936){
      int hr = s_hrow[sr];
      if (hr < 0){ av.x = av.y = av.z = av.w = 0u; }
      else av = *(const uint4*)(hb + (size_t)hr*HSTR + (gk - 480));
    } else {
      av = *(const uint4*)(tvb + (size_t)s_b[sr]*64 + (gk - 936));
    }
    *(uint4*)&As[sr*40 + sj] = av;
    *(float4*)&Bs[sr*40 + sj] = *(const float4*)&BT[(size_t)(gc0+sr)*KPP + gk];
    __syncthreads();
    bf16x8 a0 = *(const bf16x8*)&As[(wr*32      + l15)*40 + kh*8];
    bf16x8 a1 = *(const bf16x8*)&As[(wr*32 + 16 + l15)*40 + kh*8];
    bf16x8 b0 = *(const bf16x8*)&Bs[(wc*32      + l15)*40 + kh*8];
    bf16x8 b1 = *(const bf16x8*)&Bs[(wc*32 + 16 + l15)*40 + kh*8];
    acc[0][0] = __builtin_amdgcn_mfma_f32_16x16x32_bf16(a0,b0,acc[0][0],0,0,0);
    acc[0][1] = __builtin_amdgcn_mfma_f32_16x16x32_bf16(a0,b1,acc[0][1],0,0,0);
    acc[1][0] = __builtin_amdgcn_mfma_f32_16x16x32_bf16(a1,b0,acc[1][0],0,0,0);
    acc[1][1] = __builtin_amdgcn_mfma_f32_16x16x32_bf16(a1,b1,acc[1][1],0,0,0);
  }
  #pragma unroll
  for (int mi = 0; mi < 2; ++mi){
    float rowsum[4] = {0.f,0.f,0.f,0.f};
    #pragma unroll
    for (int n = 0; n < 2; ++n){
      int c = gc0 + wc*32 + n*16 + l15;
      float uc = 0.f, bc = 0.f;
      if (c < H_){ uc = Us[c]; bc = bu_[c]; }
      #pragma unroll
      for (int reg = 0; reg < 4; ++reg){
        float v = fmaxf(acc[mi][n][reg] + bc, 0.f);
        rowsum[reg] += (c < H_) ? v*uc : 0.f;
      }
    }
    #pragma unroll
    for (int reg = 0; reg < 4; ++reg){
      float pv = rowsum[reg];
      pv += __shfl_xor(pv,1); pv += __shfl_xor(pv,2);
      pv += __shfl_xor(pv,4); pv += __shfl_xor(pv,8);
      if (l15 == 0) atomicAdd(plog + gr0 + wr*32 + mi*16 + kh*4 + reg, pv);
    }
  }
}

// ---------------------------------------------------------------------------
// q reduce over bf16 logits (ld=784)
__global__ __launch_bounds__(256) void k_qreduce3(const unsigned short* __restrict__ logits,
    const int* __restrict__ q_tgt, int nq, float* __restrict__ out){
  int w = blockIdx.x*4 + (threadIdx.x>>6), lane = threadIdx.x & 63;
  int nw = gridDim.x*4;
  float qloss = 0.f, qacc = 0.f;
  for (int i = w; i < nq; i += nw){
    const uint2* lr2 = (const uint2*)(logits + (size_t)i*LDL);
    uint2 vals[4]; int cnt = 0;
    float mx = -INFINITY; int mi = 0x7fffffff;
    for (int j4 = lane; j4 < 195; j4 += 64){
      uint2 v = lr2[j4]; vals[cnt++] = v;
      float e0 = b2f(v.x), e1 = b2f(v.x>>16), e2 = b2f(v.y), e3 = b2f(v.y>>16);
      if (e0 > mx){ mx = e0; mi = j4*4; }
      if (e1 > mx){ mx = e1; mi = j4*4+1; }
      if (e2 > mx){ mx = e2; mi = j4*4+2; }
      if (e3 > mx){ mx = e3; mi = j4*4+3; }
    }
    #pragma unroll
    for (int off = 32; off; off >>= 1){
      float omx = __shfl_xor(mx, off); int omi = __shfl_xor(mi, off);
      if (omx > mx || (omx == mx && omi < mi)){ mx = omx; mi = omi; }
    }
    float ps = 0.f; cnt = 0;
    for (int j4 = lane; j4 < 195; j4 += 64){
      uint2 v = vals[cnt++];
      ps += expf(b2f(v.x)-mx) + expf(b2f(v.x>>16)-mx)
          + expf(b2f(v.y)-mx) + expf(b2f(v.y>>16)-mx);
    }
    #pragma unroll
    for (int off = 32; off; off >>= 1) ps += __shfl_xor(ps, off);
    if (lane == 0){
      int tg = q_tgt[i];
      float lt = b2f((unsigned int)logits[(size_t)i*LDL + tg]);
      qloss += mx + logf(ps) - lt;
      qacc  += (mi == tg) ? 1.f : 0.f;
    }
  }
  if (lane == 0){
    atomicAdd(out+0, qloss*(1.0f/B_));
    atomicAdd(out+2, qacc *(1.0f/(float)nq));
  }
}

// p final: BCE + acc from plog
__global__ __launch_bounds__(256) void k_pfinal(const float* __restrict__ plog,
    const float* __restrict__ bs, const int* __restrict__ p_tgt, float* __restrict__ out){
  int i = blockIdx.x*256 + threadIdx.x;
  float loss = 0.f, acc = 0.f;
  if (i < NPROWS){
    float pl = plog[i] + bs[0];
    float tgt = (float)p_tgt[i];
    loss = fmaxf(pl, 0.f) + log1pf(expf(-fabsf(pl))) - pl*tgt;
    acc = (((pl > 0.f) ? 1 : 0) == p_tgt[i]) ? 1.f : 0.f;
  }
  #pragma unroll
  for (int off = 32; off; off >>= 1){
    loss += __shfl_xor(loss, off); acc += __shfl_xor(acc, off);
  }
  if ((threadIdx.x & 63) == 0){
    atomicAdd(out+1, loss*(1.0f/B_));
    atomicAdd(out+3, acc *(1.0f/(float)NPROWS));
  }
}

// ---------------------------------------------------------------------------
extern "C" void kernel_launch(void* const* d_in, const int* in_sizes, int n_in,
                              void* d_out, int out_size, void* d_ws, size_t ws_size,
                              hipStream_t stream){
  const float* tree_vec = (const float*)d_in[0];
  const float* emb  = (const float*)d_in[1];
  const float* Wz   = (const float*)d_in[2];
  const float* bz   = (const float*)d_in[3];
  const float* Wh   = (const float*)d_in[4];
  const float* bh   = (const float*)d_in[5];
  const float* Wr   = (const float*)d_in[6];
  const float* Ur   = (const float*)d_in[7];
  const float* br   = (const float*)d_in[8];
  const float* Ww   = (const float*)d_in[9];
  const float* bw   = (const float*)d_in[10];
  const float* Uw   = (const float*)d_in[11];
  const float* bu   = (const float*)d_in[12];
  const float* Wo   = (const float*)d_in[13];
  const float* bo   = (const float*)d_in[14];
  const float* Us   = (const float*)d_in[15];
  const float* bs   = (const float*)d_in[16];
  const int* wid      = (const int*)d_in[17];
  const int* root_ids = (const int*)d_in[18];
  const int* edge_src = (const int*)d_in[19];
  const int* edge_dst = (const int*)d_in[20];
  const int* step_eid = (const int*)d_in[23];
  const int* step_v   = (const int*)d_in[24];
  const int* q_rows   = (const int*)d_in[25];
  const int* q_tgt    = (const int*)d_in[26];
  const int* p_tgt    = (const int*)d_in[27];
  int nq = in_sizes[25];           // 10240

  char* ws = (char*)d_ws;
  const size_t XB_OFF    = 0;                       // bf16 [10240][480]
  const size_t HB_OFF    = 9830400;                 // bf16 [19456][456]
  const size_t M_OFF     = 27574272;                // bf16 [19456][480]
  const size_t RM_OFF    = M_OFF + 18678784;
  const size_t HM_OFF    = RM_OFF + 18678784;       // bf16 [10240][456]
  const size_t HRM_OFF   = HM_OFF + 9338880;
  const size_t WZB_OFF   = HRM_OFF + 9338880;       // bf16 [512][480] x6 (unused by scan now)
  const size_t WHB_OFF   = WZB_OFF + 491520;
  const size_t URT_OFF   = WHB_OFF + 491520;
  const size_t WZTOP_OFF = URT_OFF + 491520;
  const size_t WHTOP_OFF = WZTOP_OFF + 491520;
  const size_t WRT_OFF   = WHTOP_OFF + 491520;
  const size_t WWT_OFF   = WRT_OFF + 491520;        // bf16 [512][512]
  const size_t UWT_OFF   = WWT_OFF + 524288;        // bf16 [512][992]
  const size_t WOT_OFF   = UWT_OFF + 1015808;       // bf16 [832][512]
  const size_t TVB_OFF   = WOT_OFF + 851968;        // bf16 [512][64]
  const size_t XWZ_OFF   = TVB_OFF + 65536;         // bf16 [10240][456] x3
  const size_t XWH_OFF   = XWZ_OFF + 9338880;
  const size_t XWR_OFF   = XWH_OFF + 9338880;
  const size_t WZQ_OFF   = XWR_OFF + 9338880;       // fp8 [512][512] x3
  const size_t WHQ_OFF   = WZQ_OFF + 262144;
  const size_t URQ_OFF   = WHQ_OFF + 262144;        // ends ~117.9 MB
  // overlays after scan:
  const size_t LQ_OFF  = M_OFF;                     // bf16 [10240][784]
  const size_t HQB_OFF = XWZ_OFF;                   // bf16 [10240][512]
  const size_t PL_OFF  = XWH_OFF;                   // f32 [19968]

  unsigned short* xb = (unsigned short*)(ws + XB_OFF);
  unsigned short* hb = (unsigned short*)(ws + HB_OFF);
  unsigned short* m_ = (unsigned short*)(ws + M_OFF);
  unsigned short* rm = (unsigned short*)(ws + RM_OFF);
  unsigned short* hm = (unsigned short*)(ws + HM_OFF);
  unsigned short* hrm = (unsigned short*)(ws + HRM_OFF);
  unsigned short* WzB = (unsigned short*)(ws + WZB_OFF);
  unsigned short* WhB = (unsigned short*)(ws + WHB_OFF);
  unsigned short* UrT = (unsigned short*)(ws + URT_OFF);
  unsigned short* WzTop = (unsigned short*)(ws + WZTOP_OFF);
  unsigned short* WhTop = (unsigned short*)(ws + WHTOP_OFF);
  unsigned short* WrT = (unsigned short*)(ws + WRT_OFF);
  unsigned short* WwT = (unsigned short*)(ws + WWT_OFF);
  unsigned short* UwT = (unsigned short*)(ws + UWT_OFF);
  unsigned short* WoT = (unsigned short*)(ws + WOT_OFF);
  unsigned short* tvb = (unsigned short*)(ws + TVB_OFF);
  unsigned short* XWz = (unsigned short*)(ws + XWZ_OFF);
  unsigned short* XWh = (unsigned short*)(ws + XWH_OFF);
  unsigned short* XWr = (unsigned short*)(ws + XWR_OFF);
  unsigned char* WzQ = (unsigned char*)(ws + WZQ_OFF);
  unsigned char* WhQ = (unsigned char*)(ws + WHQ_OFF);
  unsigned char* UrQ = (unsigned char*)(ws + URQ_OFF);

  // zero-init m, rm, hm, hrm (state + pads), out
  hipMemsetAsync(ws + M_OFF, 0, 2*18678784ull + 2*9338880ull, stream);
  hipMemsetAsync(d_out, 0, (size_t)out_size*sizeof(float), stream);

  k_gather_xb<<<2560, 256, 0, stream>>>(emb, wid, xb);
  k_wtall<<<512*8 + 832 + 512, 256, 0, stream>>>(Wz, Wh, Ur, Wr, Ww, Uw, Wo, tree_vec,
      WzB, WhB, UrT, WzTop, WhTop, WrT, WwT, UwT, WoT, tvb);
  // fp8 fragment-major scan weights (bottom halves + Ur), scale x16
  k_wt8<<<512, 256, 0, stream>>>(Wz + 450*450, 450, 450, WzQ);
  k_wt8<<<512, 256, 0, stream>>>(Wh + 450*450, 450, 450, WhQ);
  k_wt8<<<512, 256, 0, stream>>>(Ur, 450, 450, UrQ);
  k_xw<<<dim3(8,160,3), 256, 0, stream>>>(xb, WzTop, WhTop, WrT, bz, bh, br, XWz, XWh, XWr);

  // ---- scan: 256 blocks x 2 trees, fp8 GEMM operands ----
  ScanP sp;
  sp.WzQ = WzQ; sp.WhQ = WhQ; sp.UrQ = UrQ;
  sp.XWz = XWz; sp.XWh = XWh; sp.XWr = XWr;
  sp.edge_src = edge_src; sp.edge_dst = edge_dst; sp.step_eid = step_eid;
  sp.m = m_; sp.rm = rm; sp.hm = hm; sp.hrm = hrm; sp.hb = hb;
  k_scan_tree<<<B_/NT, 1024, 0, stream>>>(sp);

  // ---- q head ----
  unsigned short* logitsq = (unsigned short*)(ws + LQ_OFF);
  unsigned short* hqb     = (unsigned short*)(ws + HQB_OFF);
  float* plog             = (float*)(ws + PL_OFF);
  hipMemsetAsync(plog, 0, (size_t)NPROWS*4, stream);

  k_head_q<<<dim3(8, nq/64), 256, 0, stream>>>(hb, tvb, q_rows, WwT, bw, hqb, nq);
  k_head_mfma<<<dim3(13, nq/64), 256, 0, stream>>>(hqb, WoT, 512, bo, V_, 0,
      nullptr, 0, logitsq, LDL);
  k_qreduce3<<<320, 256, 0, stream>>>(logitsq, q_tgt, nq, (float*)d_out);

  // ---- p head ----
  k_head_p2<<<dim3(8, NPROWS/64), 256, 0, stream>>>(xb, hb, tvb, root_ids, step_v,
      UwT, bu, Us, plog);
  k_pfinal<<<78, 256, 0, stream>>>(plog, bs, p_tgt, (float*)d_out);
}

// Round 19
// 1198.244 us; speedup vs baseline: 1.4325x; 1.4325x over previous
//
#include <hip/hip_runtime.h>
#include <math.h>

#define B_ 512
#define N_ 20
#define H_ 450
#define L_ 56
#define V_ 780
#define T_ 38
#define NNODES (B_*N_)        // 10240
#define NEDGES (B_*2*(N_-1))  // 19456
#define NPROWS ((T_+1)*B_)    // 19968
#define KS 480                // m/rm/xb row stride (bf16 elements)
#define NT 2                  // trees per block -> 256 blocks (full CU coverage)
#define AST 488               // A-tile LDS row stride (shorts)
#define HSTR 456              // hb/hm/hrm/XW row stride (bf16 elements)
#define KQ 512                // q-head K: [hb 456 | tv 56]
#define KPP 992               // p-head K: [xb 480 | hb 456 | tv 56]
#define LDL 784               // logits row stride (bf16)

typedef __attribute__((ext_vector_type(8))) short bf16x8;
typedef __attribute__((ext_vector_type(4))) float f32x4;

__device__ __forceinline__ float sigmoidf_(float v){ return 1.0f/(1.0f+expf(-v)); }

__device__ __forceinline__ unsigned short f2b(float x){
  unsigned int u = __float_as_uint(x);
  unsigned int r = (u + 0x7fffu + ((u >> 16) & 1u)) >> 16;
  return (unsigned short)r;
}
__device__ __forceinline__ float b2f(unsigned int v){
  return __uint_as_float((v & 0xffffu) << 16);
}
__device__ __forceinline__ unsigned int pack2(float lo, float hi){
  return (unsigned int)f2b(lo) | ((unsigned int)f2b(hi) << 16);
}

// ---------------------------------------------------------------------------
// xb[i][:] = bf16(emb[wid[i]][:]), K-padded to 480
__global__ __launch_bounds__(256) void k_gather_xb(const float* __restrict__ emb,
    const int* __restrict__ wid, unsigned short* __restrict__ xb){
  int w = blockIdx.x*4 + (threadIdx.x>>6), lane = threadIdx.x & 63;
  if (w >= NNODES) return;
  const float2* src = (const float2*)(emb + (size_t)wid[w]*H_);
  unsigned int* dst = (unsigned int*)(xb + (size_t)w*KS);
  for (int j2 = lane; j2 < 240; j2 += 64){
    unsigned int v = 0;
    if (j2 < 225){ float2 f = src[j2]; v = pack2(f.x, f.y); }
    dst[j2] = v;
  }
}

// One fused weight-prep kernel: all transposes + tvb.
__global__ void k_wtall(const float* __restrict__ Wz, const float* __restrict__ Wh,
    const float* __restrict__ Ur, const float* __restrict__ Wr,
    const float* __restrict__ Ww, const float* __restrict__ Uw,
    const float* __restrict__ Wo, const float* __restrict__ tv,
    unsigned short* __restrict__ WzB, unsigned short* __restrict__ WhB,
    unsigned short* __restrict__ UrT, unsigned short* __restrict__ WzTop,
    unsigned short* __restrict__ WhTop, unsigned short* __restrict__ WrT,
    unsigned short* __restrict__ WwT, unsigned short* __restrict__ UwT,
    unsigned short* __restrict__ WoT, unsigned short* __restrict__ tvb){
  int bid = blockIdx.x;
  if (bid < 512*6){
    int seg = bid >> 9, c = bid & 511;
    const float* src; unsigned short* dst; int rowbase;
    switch(seg){
      case 0: src = Wz; dst = WzB; rowbase = 450; break;
      case 1: src = Wh; dst = WhB; rowbase = 450; break;
      case 2: src = Ur; dst = UrT; rowbase = 0; break;
      case 3: src = Wz; dst = WzTop; rowbase = 0; break;
      case 4: src = Wh; dst = WhTop; rowbase = 0; break;
      default: src = Wr; dst = WrT; rowbase = 0; break;
    }
    unsigned short* drow = dst + (size_t)c*KS;
    for (int k = threadIdx.x; k < KS; k += blockDim.x){
      float v = 0.f;
      if (c < 450 && k < 450) v = src[(size_t)(rowbase + k)*450 + c];
      drow[k] = f2b(v);
    }
  } else if (bid < 512*7){               // WwT: [0,456)->rows k, [456,512)->rows 450+(k-456)
    int c = bid - 512*6;
    unsigned short* drow = WwT + (size_t)c*KQ;
    for (int k = threadIdx.x; k < KQ; k += blockDim.x){
      float v = 0.f;
      if (c < 450){
        if (k < 450) v = Ww[(size_t)k*450 + c];
        else if (k >= 456) v = Ww[(size_t)(450 + k - 456)*450 + c];
      }
      drow[k] = f2b(v);
    }
  } else if (bid < 512*8){               // UwT: [0,450); [480,930)->450+(k-480); [936,992)->900+(k-936)
    int c = bid - 512*7;
    unsigned short* drow = UwT + (size_t)c*KPP;
    for (int k = threadIdx.x; k < KPP; k += blockDim.x){
      float v = 0.f;
      if (c < 450){
        if (k < 450) v = Uw[(size_t)k*450 + c];
        else if (k >= 480 && k < 930) v = Uw[(size_t)(450 + k - 480)*450 + c];
        else if (k >= 936) v = Uw[(size_t)(900 + k - 936)*450 + c];
      }
      drow[k] = f2b(v);
    }
  } else if (bid < 512*8 + 832){         // WoT straight, Kpad 512
    int c = bid - 512*8;
    unsigned short* drow = WoT + (size_t)c*512;
    for (int k = threadIdx.x; k < 512; k += blockDim.x){
      float v = 0.f;
      if (c < V_ && k < 450) v = Wo[(size_t)k*V_ + c];
      drow[k] = f2b(v);
    }
  } else {                               // tvb [512][64]
    int b = bid - (512*8 + 832);
    unsigned short* drow = tvb + (size_t)b*64;
    for (int k = threadIdx.x; k < 64; k += blockDim.x)
      drow[k] = f2b((k < L_) ? tv[b*L_ + k] : 0.f);
  }
}

// ---------------------------------------------------------------------------
struct ScanP {
  const unsigned short *WzB, *WhB, *UrT;        // bf16 [512][480] K-major
  const unsigned short *XWz, *XWh, *XWr;        // bf16 [10240][HSTR], bias folded
  const int *edge_src, *edge_dst, *step_eid;
  unsigned short *m, *rm;                       // bf16 [NEDGES][480]
  unsigned short *hm, *hrm;                     // bf16 [NNODES][HSTR]
  unsigned short *hb;                           // bf16 [T*B][HSTR]
};

// Tree-owned scan, running node accumulators, 3 barriers/step.
// NT=2 trees/block -> 256 blocks (full CU coverage).
__global__ __launch_bounds__(1024, 4) void k_scan_tree(ScanP p){
  __shared__ unsigned short A1s[16*AST];   // [s]
  __shared__ unsigned short A2s[16*AST];   // [arm]
  __shared__ unsigned short A3s[16*AST];   // [m_new]
  __shared__ unsigned short sZ[NT*HSTR], sH[NT*HSTR], sR[NT*HSTR];
  __shared__ int s_eoff[T_][NT], s_roff[T_][NT], s_srcH[T_][NT], s_dstH[T_][NT];

  const int tid = threadIdx.x;
  const int lane = tid & 63, l15 = lane & 15, kh = lane >> 4, ko = kh*8;
  const int wv = tid >> 6;
  const int r0 = blockIdx.x * NT;
  const int c_0 = wv*32 + l15, c_1 = c_0 + 16;

  const unsigned short* pWz0 = p.WzB + (size_t)c_0*KS;
  const unsigned short* pWz1 = p.WzB + (size_t)c_1*KS;
  const unsigned short* pWh0 = p.WhB + (size_t)c_0*KS;
  const unsigned short* pWh1 = p.WhB + (size_t)c_1*KS;
  const unsigned short* pUr0 = p.UrT + (size_t)c_0*KS;
  const unsigned short* pUr1 = p.UrT + (size_t)c_1*KS;
  const unsigned short* aA1 = A1s + l15*AST;
  const unsigned short* aA2 = A2s + l15*AST;
  const unsigned short* aA3 = A3s + l15*AST;

  for (int idx = tid; idx < 16*AST; idx += 1024){ A1s[idx] = 0; A2s[idx] = 0; A3s[idx] = 0; }
  for (int idx = tid; idx < T_*NT; idx += 1024){
    int t = idx / NT, rl = idx % NT;
    int e = p.step_eid[t*B_ + r0 + rl];
    s_eoff[t][rl] = e*KS;
    s_roff[t][rl] = (e ^ 1)*KS;
    s_srcH[t][rl] = p.edge_src[e]*HSTR;
    s_dstH[t][rl] = p.edge_dst[e]*HSTR;
  }
  __syncthreads();

  for (int t = 0; t < T_; ++t){
    // gate-B prefetch (hides under phase1)
    bf16x8 bz0[3], bz1[3], bh0[3], bh1[3];
    #pragma unroll
    for (int i = 0; i < 3; ++i){
      bz0[i] = *(const bf16x8*)(pWz0 + i*32 + ko);
      bz1[i] = *(const bf16x8*)(pWz1 + i*32 + ko);
      bh0[i] = *(const bf16x8*)(pWh0 + i*32 + ko);
      bh1[i] = *(const bf16x8*)(pWh1 + i*32 + ko);
    }

    // phase1: A1=[s]=hm[src]-m[rev], A2=[arm]=hrm[src]-rm[rev]; stage XW rows
    if (tid < NT*57){
      int rl = tid / 57, g = tid - rl*57;
      int j = g*8;
      uint4 hm4 = *(const uint4*)(p.hm  + s_srcH[t][rl] + j);
      uint4 hr4 = *(const uint4*)(p.hrm + s_srcH[t][rl] + j);
      uint4 mr4 = *(const uint4*)(p.m   + s_roff[t][rl] + j);
      uint4 rr4 = *(const uint4*)(p.rm  + s_roff[t][rl] + j);
      uint4 o1, o2;
      o1.x = pack2(b2f(hm4.x)-b2f(mr4.x), b2f(hm4.x>>16)-b2f(mr4.x>>16));
      o1.y = pack2(b2f(hm4.y)-b2f(mr4.y), b2f(hm4.y>>16)-b2f(mr4.y>>16));
      o1.z = pack2(b2f(hm4.z)-b2f(mr4.z), b2f(hm4.z>>16)-b2f(mr4.z>>16));
      o1.w = pack2(b2f(hm4.w)-b2f(mr4.w), b2f(hm4.w>>16)-b2f(mr4.w>>16));
      o2.x = pack2(b2f(hr4.x)-b2f(rr4.x), b2f(hr4.x>>16)-b2f(rr4.x>>16));
      o2.y = pack2(b2f(hr4.y)-b2f(rr4.y), b2f(hr4.y>>16)-b2f(rr4.y>>16));
      o2.z = pack2(b2f(hr4.z)-b2f(rr4.z), b2f(hr4.z>>16)-b2f(rr4.z>>16));
      o2.w = pack2(b2f(hr4.w)-b2f(rr4.w), b2f(hr4.w>>16)-b2f(rr4.w>>16));
      *(uint4*)(A1s + rl*AST + j) = o1;
      *(uint4*)(A2s + rl*AST + j) = o2;
    } else if (tid >= 128 && tid < 128 + 3*NT*57){
      int idx2 = tid - 128;
      int mat = idx2 / (NT*57), rem = idx2 - mat*(NT*57);
      int rl = rem / 57, g = rem - rl*57;
      int row = (mat == 2) ? s_dstH[t][rl] : s_srcH[t][rl];
      const unsigned short* src = (mat == 0) ? p.XWz : (mat == 1) ? p.XWh : p.XWr;
      unsigned short* d = (mat == 0) ? sZ : (mat == 1) ? sH : sR;
      *(uint4*)(d + rl*HSTR + g*8) = *(const uint4*)(src + row + g*8);
    }
    __syncthreads();   // (A)

    // gate K-loop
    f32x4 accZ0 = {}, accZ1 = {}, accH0 = {}, accH1 = {};
    #pragma unroll
    for (int it = 0; it < 15; ++it){
      const int sl = it % 3;
      bf16x8 a1 = *(const bf16x8*)(aA1 + it*32 + ko);
      bf16x8 a2 = *(const bf16x8*)(aA2 + it*32 + ko);
      accZ0 = __builtin_amdgcn_mfma_f32_16x16x32_bf16(a1, bz0[sl], accZ0, 0,0,0);
      accZ1 = __builtin_amdgcn_mfma_f32_16x16x32_bf16(a1, bz1[sl], accZ1, 0,0,0);
      accH0 = __builtin_amdgcn_mfma_f32_16x16x32_bf16(a2, bh0[sl], accH0, 0,0,0);
      accH1 = __builtin_amdgcn_mfma_f32_16x16x32_bf16(a2, bh1[sl], accH1, 0,0,0);
      if (it + 3 < 15){
        bz0[sl] = *(const bf16x8*)(pWz0 + (it+3)*32 + ko);
        bz1[sl] = *(const bf16x8*)(pWz1 + (it+3)*32 + ko);
        bh0[sl] = *(const bf16x8*)(pWh0 + (it+3)*32 + ko);
        bh1[sl] = *(const bf16x8*)(pWh1 + (it+3)*32 + ko);
      }
    }

    // rgate-B prefetch (overlaps epilogue1)
    bf16x8 bu0[3], bu1[3];
    #pragma unroll
    for (int i = 0; i < 3; ++i){
      bu0[i] = *(const bf16x8*)(pUr0 + i*32 + ko);
      bu1[i] = *(const bf16x8*)(pUr1 + i*32 + ko);
    }

    // epilogue1: m_new -> global m + A3s; hm RMW; hb snapshot (rows 0..NT-1)
    if (kh == 0){
      #pragma unroll
      for (int n = 0; n < 2; ++n){
        int cc = wv*32 + n*16 + l15;
        if (cc < H_){
          f32x4 aZ = n ? accZ1 : accZ0;
          f32x4 aH = n ? accH1 : accH0;
          #pragma unroll
          for (int reg = 0; reg < NT; ++reg){
            int rl = reg;
            float z  = sigmoidf_(aZ[reg] + b2f(sZ[rl*HSTR + cc]));
            float th = tanhf   (aH[reg] + b2f(sH[rl*HSTR + cc]));
            float s_ = b2f(A1s[rl*AST + cc]);
            float mn = (1.f - z)*s_ + z*th;
            unsigned short mb = f2b(mn);
            p.m[s_eoff[t][rl] + cc] = mb;
            A3s[rl*AST + cc] = mb;
            float hv = b2f(p.hm[s_dstH[t][rl] + cc]) + mn;
            p.hm[s_dstH[t][rl] + cc] = f2b(hv);
            p.hb[(size_t)(t*B_ + r0 + rl)*HSTR + cc] = f2b(hv);
          }
        }
      }
    }
    __syncthreads();   // (C) m_new in A3s complete

    // rgate K-loop: R = m_new@Ur
    f32x4 accR0 = {}, accR1 = {};
    #pragma unroll
    for (int it = 0; it < 15; ++it){
      const int sl = it % 3;
      bf16x8 a = *(const bf16x8*)(aA3 + it*32 + ko);
      accR0 = __builtin_amdgcn_mfma_f32_16x16x32_bf16(a, bu0[sl], accR0, 0,0,0);
      accR1 = __builtin_amdgcn_mfma_f32_16x16x32_bf16(a, bu1[sl], accR1, 0,0,0);
      if (it + 3 < 15){
        bu0[sl] = *(const bf16x8*)(pUr0 + (it+3)*32 + ko);
        bu1[sl] = *(const bf16x8*)(pUr1 + (it+3)*32 + ko);
      }
    }

    // epilogue2: rm store; hrm RMW
    if (kh == 0){
      #pragma unroll
      for (int n = 0; n < 2; ++n){
        int cc = wv*32 + n*16 + l15;
        if (cc < H_){
          f32x4 aR = n ? accR1 : accR0;
          #pragma unroll
          for (int reg = 0; reg < NT; ++reg){
            int rl = reg;
            float r_ = sigmoidf_(aR[reg] + b2f(sR[rl*HSTR + cc]));
            float mn = b2f(A3s[rl*AST + cc]);
            float rv = r_*mn;
            p.rm[s_eoff[t][rl] + cc] = f2b(rv);
            float hv = b2f(p.hrm[s_dstH[t][rl] + cc]) + rv;
            p.hrm[s_dstH[t][rl] + cc] = f2b(hv);
          }
        }
      }
    }
    __syncthreads();   // (D)
  }
}

// ---------------------------------------------------------------------------
// Generic head GEMM (plain A): 64x64, 4 waves, BK=32, K-major bf16 B.
__global__ __launch_bounds__(256) void k_head_mfma(
    const unsigned short* __restrict__ A, const unsigned short* __restrict__ BT, int K,
    const float* __restrict__ bias, int Nact, int relu,
    float* __restrict__ outF, int ldF, unsigned short* __restrict__ outB, int ldB)
{
  __shared__ unsigned short As[64*40], Bs[64*40];
  const int tid = threadIdx.x;
  const int gr0 = blockIdx.y*64, gc0 = blockIdx.x*64;
  const int lane = tid & 63;
  const int w = tid >> 6, wr = w >> 1, wc = w & 1;
  const int l15 = lane & 15, kh = lane >> 4;
  const int sr = tid >> 2, sj = (tid & 3) * 8;
  f32x4 acc[2][2] = {};
  for (int kt = 0; kt < K; kt += 32){
    __syncthreads();
    *(float4*)&As[sr*40 + sj] = *(const float4*)&A[(size_t)(gr0+sr)*K + kt + sj];
    *(float4*)&Bs[sr*40 + sj] = *(const float4*)&BT[(size_t)(gc0+sr)*K + kt + sj];
    __syncthreads();
    bf16x8 a0 = *(const bf16x8*)&As[(wr*32      + l15)*40 + kh*8];
    bf16x8 a1 = *(const bf16x8*)&As[(wr*32 + 16 + l15)*40 + kh*8];
    bf16x8 b0 = *(const bf16x8*)&Bs[(wc*32      + l15)*40 + kh*8];
    bf16x8 b1 = *(const bf16x8*)&Bs[(wc*32 + 16 + l15)*40 + kh*8];
    acc[0][0] = __builtin_amdgcn_mfma_f32_16x16x32_bf16(a0,b0,acc[0][0],0,0,0);
    acc[0][1] = __builtin_amdgcn_mfma_f32_16x16x32_bf16(a0,b1,acc[0][1],0,0,0);
    acc[1][0] = __builtin_amdgcn_mfma_f32_16x16x32_bf16(a1,b0,acc[1][0],0,0,0);
    acc[1][1] = __builtin_amdgcn_mfma_f32_16x16x32_bf16(a1,b1,acc[1][1],0,0,0);
  }
  #pragma unroll
  for (int mi = 0; mi < 2; ++mi){
    #pragma unroll
    for (int n = 0; n < 2; ++n){
      int c = gc0 + wc*32 + n*16 + l15;
      float bc = (c < Nact) ? bias[c] : 0.f;
      #pragma unroll
      for (int reg = 0; reg < 4; ++reg){
        int r = gr0 + wr*32 + mi*16 + kh*4 + reg;
        float v = acc[mi][n][reg] + bc;
        if (relu) v = fmaxf(v, 0.f);
        if (outF && c < Nact) outF[(size_t)r*ldF + c] = v;
        if (outB && c < ldB)  outB[(size_t)r*ldB + c] = (c < Nact) ? f2b(v) : (unsigned short)0;
      }
    }
  }
}

// XW precompute: 3 GEMMs in one launch (blockIdx.z selects matrix).
__global__ __launch_bounds__(256) void k_xw(const unsigned short* __restrict__ xb,
    const unsigned short* __restrict__ WzTop, const unsigned short* __restrict__ WhTop,
    const unsigned short* __restrict__ WrT,
    const float* __restrict__ bz, const float* __restrict__ bh, const float* __restrict__ br,
    unsigned short* __restrict__ XWz, unsigned short* __restrict__ XWh,
    unsigned short* __restrict__ XWr)
{
  __shared__ unsigned short As[64*40], Bs[64*40];
  const unsigned short* BT = (blockIdx.z == 0) ? WzTop : (blockIdx.z == 1) ? WhTop : WrT;
  const float* bias        = (blockIdx.z == 0) ? bz    : (blockIdx.z == 1) ? bh    : br;
  unsigned short* outB     = (blockIdx.z == 0) ? XWz   : (blockIdx.z == 1) ? XWh   : XWr;
  const int tid = threadIdx.x;
  const int gr0 = blockIdx.y*64, gc0 = blockIdx.x*64;
  const int lane = tid & 63;
  const int w = tid >> 6, wr = w >> 1, wc = w & 1;
  const int l15 = lane & 15, kh = lane >> 4;
  const int sr = tid >> 2, sj = (tid & 3) * 8;
  f32x4 acc[2][2] = {};
  for (int kt = 0; kt < KS; kt += 32){
    __syncthreads();
    *(float4*)&As[sr*40 + sj] = *(const float4*)&xb[(size_t)(gr0+sr)*KS + kt + sj];
    *(float4*)&Bs[sr*40 + sj] = *(const float4*)&BT[(size_t)(gc0+sr)*KS + kt + sj];
    __syncthreads();
    bf16x8 a0 = *(const bf16x8*)&As[(wr*32      + l15)*40 + kh*8];
    bf16x8 a1 = *(const bf16x8*)&As[(wr*32 + 16 + l15)*40 + kh*8];
    bf16x8 b0 = *(const bf16x8*)&Bs[(wc*32      + l15)*40 + kh*8];
    bf16x8 b1 = *(const bf16x8*)&Bs[(wc*32 + 16 + l15)*40 + kh*8];
    acc[0][0] = __builtin_amdgcn_mfma_f32_16x16x32_bf16(a0,b0,acc[0][0],0,0,0);
    acc[0][1] = __builtin_amdgcn_mfma_f32_16x16x32_bf16(a0,b1,acc[0][1],0,0,0);
    acc[1][0] = __builtin_amdgcn_mfma_f32_16x16x32_bf16(a1,b0,acc[1][0],0,0,0);
    acc[1][1] = __builtin_amdgcn_mfma_f32_16x16x32_bf16(a1,b1,acc[1][1],0,0,0);
  }
  #pragma unroll
  for (int mi = 0; mi < 2; ++mi){
    #pragma unroll
    for (int n = 0; n < 2; ++n){
      int c = gc0 + wc*32 + n*16 + l15;
      if (c >= HSTR) continue;
      float bc = (c < H_) ? bias[c] : 0.f;
      #pragma unroll
      for (int reg = 0; reg < 4; ++reg){
        int r = gr0 + wr*32 + mi*16 + kh*4 + reg;
        outB[(size_t)r*HSTR + c] = (c < H_) ? f2b(acc[mi][n][reg] + bc) : (unsigned short)0;
      }
    }
  }
}

// q-hidden GEMM with virtual A (hb|tvb via q_rows). K=512.
__global__ __launch_bounds__(256) void k_head_q(const unsigned short* __restrict__ hb,
    const unsigned short* __restrict__ tvb, const int* __restrict__ q_rows,
    const unsigned short* __restrict__ BT, const float* __restrict__ bw,
    unsigned short* __restrict__ hqb, int nq)
{
  __shared__ unsigned short As[64*40], Bs[64*40];
  __shared__ int s_hrow[64], s_b[64];
  const int tid = threadIdx.x;
  const int gr0 = blockIdx.y*64, gc0 = blockIdx.x*64;
  if (tid < 64){
    int gi = gr0 + tid;
    int row = (gi < nq) ? q_rows[gi] : 0;
    s_hrow[tid] = (row < B_) ? -1 : row - B_;
    s_b[tid] = row & (B_-1);
  }
  const int lane = tid & 63;
  const int w = tid >> 6, wr = w >> 1, wc = w & 1;
  const int l15 = lane & 15, kh = lane >> 4;
  const int sr = tid >> 2, sj = (tid & 3) * 8;
  f32x4 acc[2][2] = {};
  for (int kt = 0; kt < KQ; kt += 32){
    __syncthreads();
    int gk = kt + sj;
    uint4 av;
    if (gk < 456){
      int hr = s_hrow[sr];
      if (hr < 0){ av.x = av.y = av.z = av.w = 0u; }
      else av = *(const uint4*)(hb + (size_t)hr*HSTR + gk);
    } else {
      av = *(const uint4*)(tvb + (size_t)s_b[sr]*64 + (gk - 456));
    }
    *(uint4*)&As[sr*40 + sj] = av;
    *(float4*)&Bs[sr*40 + sj] = *(const float4*)&BT[(size_t)(gc0+sr)*KQ + gk];
    __syncthreads();
    bf16x8 a0 = *(const bf16x8*)&As[(wr*32      + l15)*40 + kh*8];
    bf16x8 a1 = *(const bf16x8*)&As[(wr*32 + 16 + l15)*40 + kh*8];
    bf16x8 b0 = *(const bf16x8*)&Bs[(wc*32      + l15)*40 + kh*8];
    bf16x8 b1 = *(const bf16x8*)&Bs[(wc*32 + 16 + l15)*40 + kh*8];
    acc[0][0] = __builtin_amdgcn_mfma_f32_16x16x32_bf16(a0,b0,acc[0][0],0,0,0);
    acc[0][1] = __builtin_amdgcn_mfma_f32_16x16x32_bf16(a0,b1,acc[0][1],0,0,0);
    acc[1][0] = __builtin_amdgcn_mfma_f32_16x16x32_bf16(a1,b0,acc[1][0],0,0,0);
    acc[1][1] = __builtin_amdgcn_mfma_f32_16x16x32_bf16(a1,b1,acc[1][1],0,0,0);
  }
  #pragma unroll
  for (int mi = 0; mi < 2; ++mi){
    #pragma unroll
    for (int n = 0; n < 2; ++n){
      int c = gc0 + wc*32 + n*16 + l15;
      float bc = (c < H_) ? bw[c] : 0.f;
      #pragma unroll
      for (int reg = 0; reg < 4; ++reg){
        int r = gr0 + wr*32 + mi*16 + kh*4 + reg;
        float v = fmaxf(acc[mi][n][reg] + bc, 0.f);
        hqb[(size_t)r*KQ + c] = (c < H_) ? f2b(v) : (unsigned short)0;
      }
    }
  }
}

// p-head GEMM with virtual A (xb|hb|tvb) + fused Us-dot. K=992.
__global__ __launch_bounds__(256) void k_head_p2(const unsigned short* __restrict__ xb,
    const unsigned short* __restrict__ hb, const unsigned short* __restrict__ tvb,
    const int* __restrict__ root_ids, const int* __restrict__ step_v,
    const unsigned short* __restrict__ BT, const float* __restrict__ bu_,
    const float* __restrict__ Us, float* __restrict__ plog)
{
  __shared__ unsigned short As[64*40], Bs[64*40];
  __shared__ int s_xrow[64], s_hrow[64], s_b[64];
  const int tid = threadIdx.x;
  const int gr0 = blockIdx.y*64, gc0 = blockIdx.x*64;
  if (tid < 64){
    int i = gr0 + tid;
    int b = i & (B_-1);
    s_b[tid] = b;
    s_xrow[tid] = (i < B_) ? root_ids[b] : step_v[i - B_];
    s_hrow[tid] = (i < B_) ? -1 : i - B_;
  }
  const int lane = tid & 63;
  const int w = tid >> 6, wr = w >> 1, wc = w & 1;
  const int l15 = lane & 15, kh = lane >> 4;
  const int sr = tid >> 2, sj = (tid & 3) * 8;
  f32x4 acc[2][2] = {};
  for (int kt = 0; kt < KPP; kt += 32){
    __syncthreads();
    int gk = kt + sj;
    uint4 av;
    if (gk < 480){
      av = *(const uint4*)(xb + (size_t)s_xrow[sr]*KS + gk);
    } else if (gk < 936){
      int hr = s_hrow[sr];
      if (hr < 0){ av.x = av.y = av.z = av.w = 0u; }
      else av = *(const uint4*)(hb + (size_t)hr*HSTR + (gk - 480));
    } else {
      av = *(const uint4*)(tvb + (size_t)s_b[sr]*64 + (gk - 936));
    }
    *(uint4*)&As[sr*40 + sj] = av;
    *(float4*)&Bs[sr*40 + sj] = *(const float4*)&BT[(size_t)(gc0+sr)*KPP + gk];
    __syncthreads();
    bf16x8 a0 = *(const bf16x8*)&As[(wr*32      + l15)*40 + kh*8];
    bf16x8 a1 = *(const bf16x8*)&As[(wr*32 + 16 + l15)*40 + kh*8];
    bf16x8 b0 = *(const bf16x8*)&Bs[(wc*32      + l15)*40 + kh*8];
    bf16x8 b1 = *(const bf16x8*)&Bs[(wc*32 + 16 + l15)*40 + kh*8];
    acc[0][0] = __builtin_amdgcn_mfma_f32_16x16x32_bf16(a0,b0,acc[0][0],0,0,0);
    acc[0][1] = __builtin_amdgcn_mfma_f32_16x16x32_bf16(a0,b1,acc[0][1],0,0,0);
    acc[1][0] = __builtin_amdgcn_mfma_f32_16x16x32_bf16(a1,b0,acc[1][0],0,0,0);
    acc[1][1] = __builtin_amdgcn_mfma_f32_16x16x32_bf16(a1,b1,acc[1][1],0,0,0);
  }
  #pragma unroll
  for (int mi = 0; mi < 2; ++mi){
    float rowsum[4] = {0.f,0.f,0.f,0.f};
    #pragma unroll
    for (int n = 0; n < 2; ++n){
      int c = gc0 + wc*32 + n*16 + l15;
      float uc = 0.f, bc = 0.f;
      if (c < H_){ uc = Us[c]; bc = bu_[c]; }
      #pragma unroll
      for (int reg = 0; reg < 4; ++reg){
        float v = fmaxf(acc[mi][n][reg] + bc, 0.f);
        rowsum[reg] += (c < H_) ? v*uc : 0.f;
      }
    }
    #pragma unroll
    for (int reg = 0; reg < 4; ++reg){
      float pv = rowsum[reg];
      pv += __shfl_xor(pv,1); pv += __shfl_xor(pv,2);
      pv += __shfl_xor(pv,4); pv += __shfl_xor(pv,8);
      if (l15 == 0) atomicAdd(plog + gr0 + wr*32 + mi*16 + kh*4 + reg, pv);
    }
  }
}

// ---------------------------------------------------------------------------
// q reduce over bf16 logits (ld=784)
__global__ __launch_bounds__(256) void k_qreduce3(const unsigned short* __restrict__ logits,
    const int* __restrict__ q_tgt, int nq, float* __restrict__ out){
  int w = blockIdx.x*4 + (threadIdx.x>>6), lane = threadIdx.x & 63;
  int nw = gridDim.x*4;
  float qloss = 0.f, qacc = 0.f;
  for (int i = w; i < nq; i += nw){
    const uint2* lr2 = (const uint2*)(logits + (size_t)i*LDL);
    uint2 vals[4]; int cnt = 0;
    float mx = -INFINITY; int mi = 0x7fffffff;
    for (int j4 = lane; j4 < 195; j4 += 64){
      uint2 v = lr2[j4]; vals[cnt++] = v;
      float e0 = b2f(v.x), e1 = b2f(v.x>>16), e2 = b2f(v.y), e3 = b2f(v.y>>16);
      if (e0 > mx){ mx = e0; mi = j4*4; }
      if (e1 > mx){ mx = e1; mi = j4*4+1; }
      if (e2 > mx){ mx = e2; mi = j4*4+2; }
      if (e3 > mx){ mx = e3; mi = j4*4+3; }
    }
    #pragma unroll
    for (int off = 32; off; off >>= 1){
      float omx = __shfl_xor(mx, off); int omi = __shfl_xor(mi, off);
      if (omx > mx || (omx == mx && omi < mi)){ mx = omx; mi = omi; }
    }
    float ps = 0.f; cnt = 0;
    for (int j4 = lane; j4 < 195; j4 += 64){
      uint2 v = vals[cnt++];
      ps += expf(b2f(v.x)-mx) + expf(b2f(v.x>>16)-mx)
          + expf(b2f(v.y)-mx) + expf(b2f(v.y>>16)-mx);
    }
    #pragma unroll
    for (int off = 32; off; off >>= 1) ps += __shfl_xor(ps, off);
    if (lane == 0){
      int tg = q_tgt[i];
      float lt = b2f((unsigned int)logits[(size_t)i*LDL + tg]);
      qloss += mx + logf(ps) - lt;
      qacc  += (mi == tg) ? 1.f : 0.f;
    }
  }
  if (lane == 0){
    atomicAdd(out+0, qloss*(1.0f/B_));
    atomicAdd(out+2, qacc *(1.0f/(float)nq));
  }
}

// p final: BCE + acc from plog
__global__ __launch_bounds__(256) void k_pfinal(const float* __restrict__ plog,
    const float* __restrict__ bs, const int* __restrict__ p_tgt, float* __restrict__ out){
  int i = blockIdx.x*256 + threadIdx.x;
  float loss = 0.f, acc = 0.f;
  if (i < NPROWS){
    float pl = plog[i] + bs[0];
    float tgt = (float)p_tgt[i];
    loss = fmaxf(pl, 0.f) + log1pf(expf(-fabsf(pl))) - pl*tgt;
    acc = (((pl > 0.f) ? 1 : 0) == p_tgt[i]) ? 1.f : 0.f;
  }
  #pragma unroll
  for (int off = 32; off; off >>= 1){
    loss += __shfl_xor(loss, off); acc += __shfl_xor(acc, off);
  }
  if ((threadIdx.x & 63) == 0){
    atomicAdd(out+1, loss*(1.0f/B_));
    atomicAdd(out+3, acc *(1.0f/(float)NPROWS));
  }
}

// ---------------------------------------------------------------------------
extern "C" void kernel_launch(void* const* d_in, const int* in_sizes, int n_in,
                              void* d_out, int out_size, void* d_ws, size_t ws_size,
                              hipStream_t stream){
  const float* tree_vec = (const float*)d_in[0];
  const float* emb  = (const float*)d_in[1];
  const float* Wz   = (const float*)d_in[2];
  const float* bz   = (const float*)d_in[3];
  const float* Wh   = (const float*)d_in[4];
  const float* bh   = (const float*)d_in[5];
  const float* Wr   = (const float*)d_in[6];
  const float* Ur   = (const float*)d_in[7];
  const float* br   = (const float*)d_in[8];
  const float* Ww   = (const float*)d_in[9];
  const float* bw   = (const float*)d_in[10];
  const float* Uw   = (const float*)d_in[11];
  const float* bu   = (const float*)d_in[12];
  const float* Wo   = (const float*)d_in[13];
  const float* bo   = (const float*)d_in[14];
  const float* Us   = (const float*)d_in[15];
  const float* bs   = (const float*)d_in[16];
  const int* wid      = (const int*)d_in[17];
  const int* root_ids = (const int*)d_in[18];
  const int* edge_src = (const int*)d_in[19];
  const int* edge_dst = (const int*)d_in[20];
  const int* step_eid = (const int*)d_in[23];
  const int* step_v   = (const int*)d_in[24];
  const int* q_rows   = (const int*)d_in[25];
  const int* q_tgt    = (const int*)d_in[26];
  const int* p_tgt    = (const int*)d_in[27];
  int nq = in_sizes[25];           // 10240

  char* ws = (char*)d_ws;
  const size_t XB_OFF    = 0;                       // bf16 [10240][480]
  const size_t HB_OFF    = 9830400;                 // bf16 [19456][456]
  const size_t M_OFF     = 27574272;                // bf16 [19456][480]
  const size_t RM_OFF    = M_OFF + 18678784;
  const size_t HM_OFF    = RM_OFF + 18678784;       // bf16 [10240][456]
  const size_t HRM_OFF   = HM_OFF + 9338880;
  const size_t WZB_OFF   = HRM_OFF + 9338880;       // bf16 [512][480] x6
  const size_t WHB_OFF   = WZB_OFF + 491520;
  const size_t URT_OFF   = WHB_OFF + 491520;
  const size_t WZTOP_OFF = URT_OFF + 491520;
  const size_t WHTOP_OFF = WZTOP_OFF + 491520;
  const size_t WRT_OFF   = WHTOP_OFF + 491520;
  const size_t WWT_OFF   = WRT_OFF + 491520;        // bf16 [512][512]
  const size_t UWT_OFF   = WWT_OFF + 524288;        // bf16 [512][992]
  const size_t WOT_OFF   = UWT_OFF + 1015808;       // bf16 [832][512]
  const size_t TVB_OFF   = WOT_OFF + 851968;        // bf16 [512][64]
  const size_t XWZ_OFF   = TVB_OFF + 65536;         // bf16 [10240][456] x3
  const size_t XWH_OFF   = XWZ_OFF + 9338880;
  const size_t XWR_OFF   = XWH_OFF + 9338880;
  // overlays after scan:
  const size_t LQ_OFF  = M_OFF;                     // bf16 [10240][784]
  const size_t HQB_OFF = XWZ_OFF;                   // bf16 [10240][512]
  const size_t PL_OFF  = XWH_OFF;                   // f32 [19968]

  unsigned short* xb = (unsigned short*)(ws + XB_OFF);
  unsigned short* hb = (unsigned short*)(ws + HB_OFF);
  unsigned short* m_ = (unsigned short*)(ws + M_OFF);
  unsigned short* rm = (unsigned short*)(ws + RM_OFF);
  unsigned short* hm = (unsigned short*)(ws + HM_OFF);
  unsigned short* hrm = (unsigned short*)(ws + HRM_OFF);
  unsigned short* WzB = (unsigned short*)(ws + WZB_OFF);
  unsigned short* WhB = (unsigned short*)(ws + WHB_OFF);
  unsigned short* UrT = (unsigned short*)(ws + URT_OFF);
  unsigned short* WzTop = (unsigned short*)(ws + WZTOP_OFF);
  unsigned short* WhTop = (unsigned short*)(ws + WHTOP_OFF);
  unsigned short* WrT = (unsigned short*)(ws + WRT_OFF);
  unsigned short* WwT = (unsigned short*)(ws + WWT_OFF);
  unsigned short* UwT = (unsigned short*)(ws + UWT_OFF);
  unsigned short* WoT = (unsigned short*)(ws + WOT_OFF);
  unsigned short* tvb = (unsigned short*)(ws + TVB_OFF);
  unsigned short* XWz = (unsigned short*)(ws + XWZ_OFF);
  unsigned short* XWh = (unsigned short*)(ws + XWH_OFF);
  unsigned short* XWr = (unsigned short*)(ws + XWR_OFF);

  // zero-init m, rm, hm, hrm (state + pads), out
  hipMemsetAsync(ws + M_OFF, 0, 2*18678784ull + 2*9338880ull, stream);
  hipMemsetAsync(d_out, 0, (size_t)out_size*sizeof(float), stream);

  k_gather_xb<<<2560, 256, 0, stream>>>(emb, wid, xb);
  k_wtall<<<512*8 + 832 + 512, 256, 0, stream>>>(Wz, Wh, Ur, Wr, Ww, Uw, Wo, tree_vec,
      WzB, WhB, UrT, WzTop, WhTop, WrT, WwT, UwT, WoT, tvb);
  k_xw<<<dim3(8,160,3), 256, 0, stream>>>(xb, WzTop, WhTop, WrT, bz, bh, br, XWz, XWh, XWr);

  // ---- scan: 256 blocks x 2 trees ----
  ScanP sp;
  sp.WzB = WzB; sp.WhB = WhB; sp.UrT = UrT;
  sp.XWz = XWz; sp.XWh = XWh; sp.XWr = XWr;
  sp.edge_src = edge_src; sp.edge_dst = edge_dst; sp.step_eid = step_eid;
  sp.m = m_; sp.rm = rm; sp.hm = hm; sp.hrm = hrm; sp.hb = hb;
  k_scan_tree<<<B_/NT, 1024, 0, stream>>>(sp);

  // ---- q head ----
  unsigned short* logitsq = (unsigned short*)(ws + LQ_OFF);
  unsigned short* hqb     = (unsigned short*)(ws + HQB_OFF);
  float* plog             = (float*)(ws + PL_OFF);
  hipMemsetAsync(plog, 0, (size_t)NPROWS*4, stream);

  k_head_q<<<dim3(8, nq/64), 256, 0, stream>>>(hb, tvb, q_rows, WwT, bw, hqb, nq);
  k_head_mfma<<<dim3(13, nq/64), 256, 0, stream>>>(hqb, WoT, 512, bo, V_, 0,
      nullptr, 0, logitsq, LDL);
  k_qreduce3<<<320, 256, 0, stream>>>(logitsq, q_tgt, nq, (float*)d_out);

  // ---- p head ----
  k_head_p2<<<dim3(8, NPROWS/64), 256, 0, stream>>>(xb, hb, tvb, root_ids, step_v,
      UwT, bu, Us, plog);
  k_pfinal<<<78, 256, 0, stream>>>(plog, bs, p_tgt, (float*)d_out);
}